// Round 1
// baseline (6732.512 us; speedup 1.0000x reference)
//
#include <hip/hip_runtime.h>
#include <hip/hip_bf16.h>
#include <stdint.h>

// Problem constants
#define B_   64
#define S_   512
#define DIN  512
#define DH   1024
#define KTOT (DIN + DH)      // 1536
#define NBG  4               // batch groups (16 batches each)
#define NCG  32              // col groups (32 cols each)
#define BBLK 16
#define CBLK 32
#define NKC  (KTOT / 32)     // 48 k-chunks of 32
#define NKX  (DIN / 32)      // 16 x k-chunks
#define NKH  (DH / 32)       // 32 h k-chunks
#define NFLG (NCG * 4)       // per-producer-wave flags per (bg, t) = 128

typedef __bf16 bf16x8 __attribute__((ext_vector_type(8)));
typedef float f32x4 __attribute__((ext_vector_type(4)));
typedef unsigned short ushort8v __attribute__((ext_vector_type(8)));
typedef unsigned short ushort4v __attribute__((ext_vector_type(4)));

static __device__ __forceinline__ unsigned short f2bf(float f) {
    union { __bf16 b; unsigned short u; } v; v.b = (__bf16)f; return v.u;
}
static __device__ __forceinline__ float fast_tanh(float x) {
    // 1 - 2/(e^{2x}+1): exact at +/-inf, no NaN from inf/inf
    float e = __expf(2.0f * x);
    return 1.0f - 2.0f / (e + 1.0f);
}

// ---------------- convert x (fp32 -> bf16), 4 elems/thread ----------------
__global__ void k_cvt_bf16(const float* __restrict__ src,
                           unsigned short* __restrict__ dst, int n4) {
    int i = blockIdx.x * blockDim.x + threadIdx.x;
    if (i < n4) {
        float4 v = ((const float4*)src)[i];
        ushort4v o;
        o.x = f2bf(v.x); o.y = f2bf(v.y); o.z = f2bf(v.z); o.w = f2bf(v.w);
        ((ushort4v*)dst)[i] = o;
    }
}

// ------- swizzle W (fp32 [1536][1024]) into B-fragment order, bf16 -------
// layout: [kc(48)][ntg(64)][lane(64)][8] ; frag elem i = W[kc*32+q*8+i][ntg*16+n16]
__global__ void k_swz_w(const float* __restrict__ W,
                        unsigned short* __restrict__ dst) {
    int u = blockIdx.x * blockDim.x + threadIdx.x;   // 48*64*64 = 196608
    int lane = u & 63;
    int ntg  = (u >> 6) & 63;
    int kc   = u >> 12;
    int q = lane >> 4, n16 = lane & 15;
    int k0 = kc * 32 + q * 8;
    int n  = ntg * 16 + n16;
    ushort8v o;
#pragma unroll
    for (int i = 0; i < 8; ++i) o[i] = f2bf(W[(size_t)(k0 + i) * DH + n]);
    *(ushort8v*)(dst + (size_t)u * 8) = o;
}

// ---------------- persistent recurrence kernel ----------------
// ldsA holds ONLY the h-part of A (K = 1024), bf16
#define SMEM_A_PITCH 1032                        // 1024 + 8 pad (ushorts)
#define SMEM_A_USH   (16 * SMEM_A_PITCH)         // 16512
#define SMEM_W_USH   (NKC * 2 * 64 * 8)          // 49152
#define SMEM_P_PITCH 34                          // floats, conflict-free
#define SMEM_P_FLT   (4 * 16 * SMEM_P_PITCH)     // 2176
#define SMEM_BYTES   (SMEM_A_USH * 2 + SMEM_W_USH * 2 + SMEM_P_FLT * 4)  // 140032

__global__ __launch_bounds__(256, 1) void k_rnn(
    const unsigned short* __restrict__ xb,    // [B][S][DIN] bf16
    const unsigned short* __restrict__ wswz,  // swizzled W bf16
    const float* __restrict__ h0,             // [B][DH] fp32
    const float* __restrict__ bias,           // [DH] fp32
    float* __restrict__ out,                  // outs [B][S][DH] + h_last [B][DH]
    unsigned int* ring,                       // [2][B][DH/2] bf16-pairs
    int* flags)                               // [NBG][S][NFLG] per-producer-wave
{
    extern __shared__ char smem[];
    unsigned short* ldsA = (unsigned short*)smem;
    unsigned short* ldsW = (unsigned short*)(smem + SMEM_A_USH * 2);
    float* ldsP = (float*)(smem + SMEM_A_USH * 2 + SMEM_W_USH * 2);

    const int tid = threadIdx.x;
    // XCD-grouped mapping: each bg's 32 WGs land on 2 XCDs (blockIdx%8 -> XCD)
    const int bg = blockIdx.x & 3;
    const int cg = blockIdx.x >> 2;
    const int b0 = bg * BBLK;
    const int c0 = cg * CBLK;
    const int lane = tid & 63;
    const int wv = tid >> 6;
    const int q = lane >> 4;
    const int m16 = lane & 15;

    // one-time: preload this WG's W slice (already frag-swizzled, contiguous)
    for (int c = tid; c < NKC * 2 * 64; c += 256) {
        int kc = c >> 7;
        int rem = c & 127;
        int l = rem >> 6;
        int ln = rem & 63;
        size_t src = ((size_t)(kc * 64 + 2 * cg + l) * 64 + ln) * 8;
        int dst = ((kc * 2 + l) * 64 + ln) * 8;
        *(ushort8v*)(ldsW + dst) = *(const ushort8v*)(wswz + src);
    }

    const int em = tid >> 4;          // epilogue row 0..15
    const int np = (tid & 15) * 2;    // epilogue col pair 0..30
    const float bias0 = bias[c0 + np];
    const float bias1 = bias[c0 + np + 1];

    __syncthreads();

    for (int t = 0; t < S_; ++t) {
        // ---- x-part MFMA (K = 0..511), A-frags straight from global (read-only,
        //      cached); runs BEFORE the flag wait so it is off the critical chain.
        f32x4 acc0 = {0.f, 0.f, 0.f, 0.f}, acc1 = {0.f, 0.f, 0.f, 0.f};
        {
            bf16x8 ax[4];
            const unsigned short* xrow =
                xb + ((size_t)(b0 + m16) * S_ + t) * DIN + q * 8;
#pragma unroll
            for (int kk = 0; kk < 4; ++kk)
                ax[kk] = *(const bf16x8*)(xrow + (wv * 4 + kk) * 32);
#pragma unroll
            for (int kk = 0; kk < 4; ++kk) {
                int kc = wv * 4 + kk;
                bf16x8 bb0 = *(const bf16x8*)(ldsW + ((kc * 2 + 0) * 64 + lane) * 8);
                bf16x8 bb1 = *(const bf16x8*)(ldsW + ((kc * 2 + 1) * 64 + lane) * 8);
                acc0 = __builtin_amdgcn_mfma_f32_16x16x32_bf16(ax[kk], bb0, acc0, 0, 0, 0);
                acc1 = __builtin_amdgcn_mfma_f32_16x16x32_bf16(ax[kk], bb1, acc1, 0, 0, 0);
            }
        }

        // ---- wait for h_{t-1}: all threads poll 128 per-producer-wave flags
        if (t > 0) {
            int* fb = flags + ((size_t)bg * S_ + (t - 1)) * NFLG;
            for (;;) {
                int f0 = __hip_atomic_load(fb + lane, __ATOMIC_RELAXED,
                                           __HIP_MEMORY_SCOPE_AGENT);
                int f1 = __hip_atomic_load(fb + lane + 64, __ATOMIC_RELAXED,
                                           __HIP_MEMORY_SCOPE_AGENT);
                if (__all(f0 && f1)) break;
                __builtin_amdgcn_s_sleep(1);
            }
            __builtin_amdgcn_fence(__ATOMIC_ACQUIRE, "agent");
        }

        // ---- stage h_{t-1} -> ldsA (bf16, u64-wide)
        if (t == 0) {
#pragma unroll
            for (int i = 0; i < 32; ++i) {
                int c = tid + i * 256;
                int row = c >> 9, off2 = c & 511;
                const float2 v = *(const float2*)(h0 + (size_t)(b0 + row) * DH + off2 * 2);
                unsigned int pk = (unsigned int)f2bf(v.x) | ((unsigned int)f2bf(v.y) << 16);
                *(unsigned int*)(ldsA + row * SMEM_A_PITCH + off2 * 2) = pk;
            }
        } else {
            const unsigned long long* rg =
                (const unsigned long long*)(ring + ((t - 1) & 1) * (B_ * (DH / 2)));
            unsigned long long hv[16];
#pragma unroll
            for (int i = 0; i < 16; ++i) {           // issue all loads first (ILP)
                int c = tid + i * 256;
                int row = c >> 8, off = c & 255;
                hv[i] = __hip_atomic_load(rg + (size_t)(b0 + row) * 256 + off,
                                          __ATOMIC_RELAXED, __HIP_MEMORY_SCOPE_AGENT);
            }
#pragma unroll
            for (int i = 0; i < 16; ++i) {
                int c = tid + i * 256;
                int row = c >> 8, off = c & 255;
                *(unsigned long long*)(ldsA + row * SMEM_A_PITCH + off * 4) = hv[i];
            }
        }
        __syncthreads();

        // ---- h-part MFMA (K = 512..1535): K-split over 4 waves, 8 k-chunks each
#pragma unroll
        for (int kk = 0; kk < 8; ++kk) {
            int kh = wv * 8 + kk;          // 0..31 within h region
            int kc = NKX + kh;             // 16..47 global k-chunk (for W)
            bf16x8 a   = *(const bf16x8*)(ldsA + m16 * SMEM_A_PITCH + kh * 32 + q * 8);
            bf16x8 bb0 = *(const bf16x8*)(ldsW + ((kc * 2 + 0) * 64 + lane) * 8);
            bf16x8 bb1 = *(const bf16x8*)(ldsW + ((kc * 2 + 1) * 64 + lane) * 8);
            acc0 = __builtin_amdgcn_mfma_f32_16x16x32_bf16(a, bb0, acc0, 0, 0, 0);
            acc1 = __builtin_amdgcn_mfma_f32_16x16x32_bf16(a, bb1, acc1, 0, 0, 0);
        }
#pragma unroll
        for (int i = 0; i < 4; ++i) {
            ldsP[wv * 544 + (q * 4 + i) * SMEM_P_PITCH + m16]      = acc0[i];
            ldsP[wv * 544 + (q * 4 + i) * SMEM_P_PITCH + 16 + m16] = acc1[i];
        }
        __syncthreads();

        // ---- epilogue: reduce 4 wave-partials, bias, tanh, publish FIRST
        float s0 = bias0, s1 = bias1;
#pragma unroll
        for (int w = 0; w < 4; ++w) {
            const float2 p = *(const float2*)(ldsP + w * 544 + em * SMEM_P_PITCH + np);
            s0 += p.x; s1 += p.y;
        }
        float v0 = fast_tanh(s0), v1 = fast_tanh(s1);

        // ring publish (agent-scope, goes to coherence point)
        unsigned int pk = (unsigned int)f2bf(v0) | ((unsigned int)f2bf(v1) << 16);
        unsigned int* rw = ring + (t & 1) * (B_ * (DH / 2));
        __hip_atomic_store(rw + (size_t)(b0 + em) * (DH / 2) + (c0 + np) / 2, pk,
                           __ATOMIC_RELAXED, __HIP_MEMORY_SCOPE_AGENT);

        // per-wave release: lane0's release-store drains this wave's vmcnt, so
        // this wave's ring rows (em = 4*wv..4*wv+3) are visible before its flag.
        if ((tid & 63) == 0)
            __hip_atomic_store(flags + ((size_t)bg * S_ + t) * NFLG + cg * 4 + wv, 1,
                               __ATOMIC_RELEASE, __HIP_MEMORY_SCOPE_AGENT);

        // HBM out-store AFTER the flag: off the inter-WG critical chain
        float2 ov; ov.x = v0; ov.y = v1;
        *(float2*)(out + ((size_t)(b0 + em) * S_ + t) * DH + c0 + np) = ov;
        if (t == S_ - 1)
            *(float2*)(out + (size_t)B_ * S_ * DH + (size_t)(b0 + em) * DH + c0 + np) = ov;
        // no trailing barrier: next iteration's first LDS touch (h-stage) is
        // ordered against this step's reads by the partial-store barrier above.
    }
}

extern "C" void kernel_launch(void* const* d_in, const int* in_sizes, int n_in,
                              void* d_out, int out_size, void* d_ws, size_t ws_size,
                              hipStream_t stream) {
    const float* x  = (const float*)d_in[0];   // [64][512][512]
    const float* h0 = (const float*)d_in[1];   // [64][1024]
    const float* W  = (const float*)d_in[2];   // [1536][1024]
    const float* b  = (const float*)d_in[3];   // [1024]
    float* out = (float*)d_out;

    // workspace layout
    char* ws = (char*)d_ws;
    int* flags = (int*)ws;                                          // 1 MB
    unsigned int* ring = (unsigned int*)(ws + (1 << 20));           // 256 KB
    unsigned short* xb = (unsigned short*)(ws + (1 << 20) + (1 << 18)); // 32 MB
    unsigned short* wswz = xb + (size_t)B_ * S_ * DIN;              // 3 MB

    (void)hipFuncSetAttribute((const void*)k_rnn,
                              hipFuncAttributeMaxDynamicSharedMemorySize,
                              SMEM_BYTES);

    hipMemsetAsync(flags, 0, (size_t)NBG * S_ * NFLG * sizeof(int), stream);
    k_cvt_bf16<<<(B_ * S_ * DIN / 4 + 255) / 256, 256, 0, stream>>>(x, xb, B_ * S_ * DIN / 4);
    k_swz_w<<<(NKC * 64 * 64) / 256, 256, 0, stream>>>(W, wswz);
    k_rnn<<<NBG * NCG, 256, SMEM_BYTES, stream>>>(xb, wswz, h0, b, out, ring, flags);
}

// Round 2
// 3142.176 us; speedup vs baseline: 2.1426x; 2.1426x over previous
//
#include <hip/hip_runtime.h>
#include <hip/hip_bf16.h>
#include <stdint.h>

// Problem constants
#define B_   64
#define S_   512
#define DIN  512
#define DH   1024
#define KTOT (DIN + DH)      // 1536
#define NBG  4               // batch groups (16 batches each)
#define NCG  32              // col groups (32 cols each)
#define BBLK 16
#define CBLK 32
#define NKC  (KTOT / 32)     // 48 k-chunks of 32
#define NKX  (DIN / 32)      // 16 x k-chunks

typedef __bf16 bf16x8 __attribute__((ext_vector_type(8)));
typedef float f32x4 __attribute__((ext_vector_type(4)));
typedef unsigned short ushort8v __attribute__((ext_vector_type(8)));
typedef unsigned short ushort4v __attribute__((ext_vector_type(4)));

static __device__ __forceinline__ unsigned short f2bf(float f) {
    union { __bf16 b; unsigned short u; } v; v.b = (__bf16)f; return v.u;
}
static __device__ __forceinline__ float fast_tanh(float x) {
    // 1 - 2/(e^{2x}+1): exact at +/-inf, no NaN from inf/inf
    float e = __expf(2.0f * x);
    return 1.0f - 2.0f / (e + 1.0f);
}

// ---------------- convert x (fp32 -> bf16), 4 elems/thread ----------------
__global__ void k_cvt_bf16(const float* __restrict__ src,
                           unsigned short* __restrict__ dst, int n4) {
    int i = blockIdx.x * blockDim.x + threadIdx.x;
    if (i < n4) {
        float4 v = ((const float4*)src)[i];
        ushort4v o;
        o.x = f2bf(v.x); o.y = f2bf(v.y); o.z = f2bf(v.z); o.w = f2bf(v.w);
        ((ushort4v*)dst)[i] = o;
    }
}

// ------- swizzle W (fp32 [1536][1024]) into B-fragment order, bf16 -------
// layout: [kc(48)][ntg(64)][lane(64)][8] ; frag elem i = W[kc*32+q*8+i][ntg*16+n16]
__global__ void k_swz_w(const float* __restrict__ W,
                        unsigned short* __restrict__ dst) {
    int u = blockIdx.x * blockDim.x + threadIdx.x;   // 48*64*64 = 196608
    int lane = u & 63;
    int ntg  = (u >> 6) & 63;
    int kc   = u >> 12;
    int q = lane >> 4, n16 = lane & 15;
    int k0 = kc * 32 + q * 8;
    int n  = ntg * 16 + n16;
    ushort8v o;
#pragma unroll
    for (int i = 0; i < 8; ++i) o[i] = f2bf(W[(size_t)(k0 + i) * DH + n]);
    *(ushort8v*)(dst + (size_t)u * 8) = o;
}

// ---------------- persistent recurrence kernel ----------------
// LDS: only W fragments + partial buffer. No A staging at all.
#define SMEM_W_USH   (NKC * 2 * 64 * 8)          // 49152 ushorts
#define SMEM_P_PITCH 34                          // floats, conflict-light
#define SMEM_P_FLT   (4 * 16 * SMEM_P_PITCH)     // 2176 floats
#define SMEM_BYTES   (SMEM_W_USH * 2 + SMEM_P_FLT * 4)  // 107008

__global__ __launch_bounds__(256, 1) void k_rnn(
    const unsigned short* __restrict__ xb,    // [B][S][DIN] bf16
    const unsigned short* __restrict__ wswz,  // swizzled W bf16
    const float* __restrict__ h0,             // [B][DH] fp32
    const float* __restrict__ bias,           // [DH] fp32
    float* __restrict__ out,                  // outs [B][S][DH] + h_last [B][DH]
    unsigned int* ring,                       // [2][B][DH/2] bf16-pairs
    int* flags)                               // [NBG][S][32] one flag per producer WG
{
    extern __shared__ char smem[];
    unsigned short* ldsW = (unsigned short*)smem;
    float* ldsP = (float*)(smem + SMEM_W_USH * 2);

    const int tid = threadIdx.x;
    const int bg = blockIdx.x >> 5;        // baseline mapping (known-good)
    const int cg = blockIdx.x & 31;
    const int b0 = bg * BBLK;
    const int c0 = cg * CBLK;
    const int lane = tid & 63;
    const int wv = tid >> 6;
    const int q = lane >> 4;
    const int m16 = lane & 15;

    // one-time: preload this WG's W slice (already frag-swizzled, contiguous)
    for (int c = tid; c < NKC * 2 * 64; c += 256) {
        int kc = c >> 7;
        int rem = c & 127;
        int l = rem >> 6;
        int ln = rem & 63;
        size_t src = ((size_t)(kc * 64 + 2 * cg + l) * 64 + ln) * 8;
        int dst = ((kc * 2 + l) * 64 + ln) * 8;
        *(ushort8v*)(ldsW + dst) = *(const ushort8v*)(wswz + src);
    }

    const int em = tid >> 4;          // epilogue row 0..15
    const int np = (tid & 15) * 2;    // epilogue col pair 0..30
    const float bias0 = bias[c0 + np];
    const float bias1 = bias[c0 + np + 1];

    __syncthreads();

    for (int t = 0; t < S_; ++t) {
        // ---- x-part MFMA (K = 0..511): A-frags straight from global (cached,
        //      read-only); runs BEFORE the wait, off the critical chain.
        f32x4 acc0 = {0.f, 0.f, 0.f, 0.f}, acc1 = {0.f, 0.f, 0.f, 0.f};
        {
            bf16x8 ax[4];
            const unsigned short* xrow =
                xb + ((size_t)(b0 + m16) * S_ + t) * DIN + q * 8;
#pragma unroll
            for (int kk = 0; kk < 4; ++kk)
                ax[kk] = *(const bf16x8*)(xrow + (wv * 4 + kk) * 32);
#pragma unroll
            for (int kk = 0; kk < 4; ++kk) {
                int kc = wv * 4 + kk;
                bf16x8 bb0 = *(const bf16x8*)(ldsW + ((kc * 2 + 0) * 64 + lane) * 8);
                bf16x8 bb1 = *(const bf16x8*)(ldsW + ((kc * 2 + 1) * 64 + lane) * 8);
                acc0 = __builtin_amdgcn_mfma_f32_16x16x32_bf16(ax[kk], bb0, acc0, 0, 0, 0);
                acc1 = __builtin_amdgcn_mfma_f32_16x16x32_bf16(ax[kk], bb1, acc1, 0, 0, 0);
            }
        }

        // ---- wait for h_{t-1}: wave0 polls the 32-flag line (one coalesced
        //      load + ballot); other waves park at the barrier.
        if (t > 0) {
            if (wv == 0) {
                const int* fb = flags + ((size_t)bg * S_ + (t - 1)) * 32;
                for (;;) {
                    int f = __hip_atomic_load(fb + (lane & 31), __ATOMIC_RELAXED,
                                              __HIP_MEMORY_SCOPE_AGENT);
                    if (__all(f != 0)) break;
                    __builtin_amdgcn_s_sleep(1);
                }
            }
            __syncthreads();
        }

        // ---- h-part A-fragments DIRECT to registers (no LDS staging)
        // lane (wv,q,m16) needs h[b0+m16][(NKX+wv*8+kk)*32 - 512 + q*8 .. +7]
        bf16x8 ah[8];
        if (t == 0) {
            const float* hrow = h0 + (size_t)(b0 + m16) * DH + q * 8;
#pragma unroll
            for (int kk = 0; kk < 8; ++kk) {
                const float* p = hrow + (wv * 8 + kk) * 32;
                float4 lo = *(const float4*)(p);
                float4 hi = *(const float4*)(p + 4);
                union { ushort8v s; bf16x8 v; } cv;
                cv.s[0] = f2bf(lo.x); cv.s[1] = f2bf(lo.y);
                cv.s[2] = f2bf(lo.z); cv.s[3] = f2bf(lo.w);
                cv.s[4] = f2bf(hi.x); cv.s[5] = f2bf(hi.y);
                cv.s[6] = f2bf(hi.z); cv.s[7] = f2bf(hi.w);
                ah[kk] = cv.v;
            }
        } else {
            const unsigned long long* rg =
                (const unsigned long long*)(ring + ((t - 1) & 1) * (B_ * (DH / 2)));
            const size_t base = (size_t)(b0 + m16) * 256 + wv * 64 + q * 2;
            unsigned long long w0[8], w1[8];
#pragma unroll
            for (int kk = 0; kk < 8; ++kk) {         // issue all 16 loads, 1 RTT
                w0[kk] = __hip_atomic_load(rg + base + kk * 8, __ATOMIC_RELAXED,
                                           __HIP_MEMORY_SCOPE_AGENT);
                w1[kk] = __hip_atomic_load(rg + base + kk * 8 + 1, __ATOMIC_RELAXED,
                                           __HIP_MEMORY_SCOPE_AGENT);
            }
#pragma unroll
            for (int kk = 0; kk < 8; ++kk) {
                union { unsigned long long u[2]; bf16x8 v; } cv;
                cv.u[0] = w0[kk]; cv.u[1] = w1[kk];
                ah[kk] = cv.v;
            }
        }

        // ---- h-part MFMA (K = 512..1535): K-split over 4 waves, 8 k-chunks each
#pragma unroll
        for (int kk = 0; kk < 8; ++kk) {
            int kc = NKX + wv * 8 + kk;
            bf16x8 bb0 = *(const bf16x8*)(ldsW + ((kc * 2 + 0) * 64 + lane) * 8);
            bf16x8 bb1 = *(const bf16x8*)(ldsW + ((kc * 2 + 1) * 64 + lane) * 8);
            acc0 = __builtin_amdgcn_mfma_f32_16x16x32_bf16(ah[kk], bb0, acc0, 0, 0, 0);
            acc1 = __builtin_amdgcn_mfma_f32_16x16x32_bf16(ah[kk], bb1, acc1, 0, 0, 0);
        }
#pragma unroll
        for (int i = 0; i < 4; ++i) {
            ldsP[wv * (16 * SMEM_P_PITCH) + (q * 4 + i) * SMEM_P_PITCH + m16]      = acc0[i];
            ldsP[wv * (16 * SMEM_P_PITCH) + (q * 4 + i) * SMEM_P_PITCH + 16 + m16] = acc1[i];
        }
        __syncthreads();

        // ---- epilogue: reduce 4 wave-partials, bias, tanh
        float s0 = bias0, s1 = bias1;
#pragma unroll
        for (int w = 0; w < 4; ++w) {
            const float2 p = *(const float2*)(ldsP + w * (16 * SMEM_P_PITCH) +
                                              em * SMEM_P_PITCH + np);
            s0 += p.x; s1 += p.y;
        }
        float v0 = fast_tanh(s0), v1 = fast_tanh(s1);

        // ring publish (agent-scope -> LLC)
        unsigned int pk = (unsigned int)f2bf(v0) | ((unsigned int)f2bf(v1) << 16);
        unsigned int* rw = ring + (t & 1) * (B_ * (DH / 2));
        __hip_atomic_store(rw + (size_t)(b0 + em) * (DH / 2) + (c0 + np) / 2, pk,
                           __ATOMIC_RELAXED, __HIP_MEMORY_SCOPE_AGENT);

        // barrier drains every wave's ring store (vmcnt(0) in __syncthreads),
        // then ONE release store per WG publishes the step. No RMW.
        __syncthreads();
        if (tid == 0)
            __hip_atomic_store(flags + ((size_t)bg * S_ + t) * 32 + cg, 1,
                               __ATOMIC_RELEASE, __HIP_MEMORY_SCOPE_AGENT);

        // HBM out-store AFTER the publish: off the inter-WG critical chain
        float2 ov; ov.x = v0; ov.y = v1;
        *(float2*)(out + ((size_t)(b0 + em) * S_ + t) * DH + c0 + np) = ov;
        if (t == S_ - 1)
            *(float2*)(out + (size_t)B_ * S_ * DH + (size_t)(b0 + em) * DH + c0 + np) = ov;
    }
}

extern "C" void kernel_launch(void* const* d_in, const int* in_sizes, int n_in,
                              void* d_out, int out_size, void* d_ws, size_t ws_size,
                              hipStream_t stream) {
    const float* x  = (const float*)d_in[0];   // [64][512][512]
    const float* h0 = (const float*)d_in[1];   // [64][1024]
    const float* W  = (const float*)d_in[2];   // [1536][1024]
    const float* b  = (const float*)d_in[3];   // [1024]
    float* out = (float*)d_out;

    // workspace layout
    char* ws = (char*)d_ws;
    int* flags = (int*)ws;                                          // 256 KB
    unsigned int* ring = (unsigned int*)(ws + 262144);              // 256 KB
    unsigned short* xb = (unsigned short*)(ws + 524288);            // 32 MB
    unsigned short* wswz = xb + (size_t)B_ * S_ * DIN;              // 3 MB

    (void)hipFuncSetAttribute((const void*)k_rnn,
                              hipFuncAttributeMaxDynamicSharedMemorySize,
                              SMEM_BYTES);

    hipMemsetAsync(flags, 0, (size_t)NBG * S_ * 32 * sizeof(int), stream);
    k_cvt_bf16<<<(B_ * S_ * DIN / 4 + 255) / 256, 256, 0, stream>>>(x, xb, B_ * S_ * DIN / 4);
    k_swz_w<<<(NKC * 64 * 64) / 256, 256, 0, stream>>>(W, wswz);
    k_rnn<<<NBG * NCG, 256, SMEM_BYTES, stream>>>(xb, wswz, h0, b, out, ring, flags);
}

// Round 3
// 2732.812 us; speedup vs baseline: 2.4636x; 1.1498x over previous
//
#include <hip/hip_runtime.h>
#include <hip/hip_bf16.h>
#include <stdint.h>

// Problem constants
#define B_   64
#define S_   512
#define DIN  512
#define DH   1024
#define KTOT (DIN + DH)      // 1536
#define NBG  4               // batch groups (16 batches each)
#define NCG  32              // col groups (32 cols each)
#define BBLK 16
#define CBLK 32
#define NKC  (KTOT / 32)     // 48 k-chunks of 32
#define NKX  (DIN / 32)      // 16 x k-chunks

#define RING_SLOT (B_ * (DH / 2))   // 32768 u32 per slot
#define NSLOT 4
#define SENT  0xFFFFFFFFu           // bf16 NaN pair; tanh output can never be NaN

typedef __bf16 bf16x8 __attribute__((ext_vector_type(8)));
typedef float f32x4 __attribute__((ext_vector_type(4)));
typedef unsigned short ushort8v __attribute__((ext_vector_type(8)));
typedef unsigned short ushort4v __attribute__((ext_vector_type(4)));

static __device__ __forceinline__ unsigned short f2bf(float f) {
    union { __bf16 b; unsigned short u; } v; v.b = (__bf16)f; return v.u;
}
static __device__ __forceinline__ float fast_tanh(float x) {
    // 1 - 2/(e^{2x}+1): exact at +/-inf, no NaN from inf/inf
    float e = __expf(2.0f * x);
    return 1.0f - 2.0f / (e + 1.0f);
}

// ---------------- convert x (fp32 -> bf16), 4 elems/thread ----------------
__global__ void k_cvt_bf16(const float* __restrict__ src,
                           unsigned short* __restrict__ dst, int n4) {
    int i = blockIdx.x * blockDim.x + threadIdx.x;
    if (i < n4) {
        float4 v = ((const float4*)src)[i];
        ushort4v o;
        o.x = f2bf(v.x); o.y = f2bf(v.y); o.z = f2bf(v.z); o.w = f2bf(v.w);
        ((ushort4v*)dst)[i] = o;
    }
}

// ------- swizzle W (fp32 [1536][1024]) into B-fragment order, bf16 -------
// layout: [kc(48)][ntg(64)][lane(64)][8] ; frag elem i = W[kc*32+q*8+i][ntg*16+n16]
__global__ void k_swz_w(const float* __restrict__ W,
                        unsigned short* __restrict__ dst) {
    int u = blockIdx.x * blockDim.x + threadIdx.x;   // 48*64*64 = 196608
    int lane = u & 63;
    int ntg  = (u >> 6) & 63;
    int kc   = u >> 12;
    int q = lane >> 4, n16 = lane & 15;
    int k0 = kc * 32 + q * 8;
    int n  = ntg * 16 + n16;
    ushort8v o;
#pragma unroll
    for (int i = 0; i < 8; ++i) o[i] = f2bf(W[(size_t)(k0 + i) * DH + n]);
    *(ushort8v*)(dst + (size_t)u * 8) = o;
}

// ---------------- persistent recurrence kernel ----------------
#define SMEM_W_USH   (NKC * 2 * 64 * 8)          // 49152 ushorts
#define SMEM_P_PITCH 34                          // floats, conflict-light
#define SMEM_P_FLT   (4 * 16 * SMEM_P_PITCH)     // 2176 floats
#define SMEM_BYTES   (SMEM_W_USH * 2 + SMEM_P_FLT * 4)  // 107008

__global__ __launch_bounds__(256, 1) void k_rnn(
    const unsigned short* __restrict__ xb,    // [B][S][DIN] bf16
    const unsigned short* __restrict__ wswz,  // swizzled W bf16
    const float* __restrict__ h0,             // [B][DH] fp32
    const float* __restrict__ bias,           // [DH] fp32
    float* __restrict__ out,                  // outs [B][S][DH] + h_last [B][DH]
    unsigned int* ring)                       // [NSLOT][B][DH/2] bf16-pairs, sentinel-init
{
    extern __shared__ char smem[];
    unsigned short* ldsW = (unsigned short*)smem;
    float* ldsP = (float*)(smem + SMEM_W_USH * 2);

    const int tid = threadIdx.x;
    const int bg = blockIdx.x >> 5;
    const int cg = blockIdx.x & 31;
    const int b0 = bg * BBLK;
    const int c0 = cg * CBLK;
    const int lane = tid & 63;
    const int wv = tid >> 6;
    const int q = lane >> 4;
    const int m16 = lane & 15;

    // one-time: preload this WG's W slice (already frag-swizzled, contiguous)
    for (int c = tid; c < NKC * 2 * 64; c += 256) {
        int kc = c >> 7;
        int rem = c & 127;
        int l = rem >> 6;
        int ln = rem & 63;
        size_t src = ((size_t)(kc * 64 + 2 * cg + l) * 64 + ln) * 8;
        int dst = ((kc * 2 + l) * 64 + ln) * 8;
        *(ushort8v*)(ldsW + dst) = *(const ushort8v*)(wswz + src);
    }

    const int em = tid >> 4;          // epilogue row 0..15
    const int np = (tid & 15) * 2;    // epilogue col pair 0..30
    const float bias0 = bias[c0 + np];
    const float bias1 = bias[c0 + np + 1];

    // lane's h u64-index base: row (b0+m16), cols (wv*8+kk)*32 + q*8 .. +7
    const size_t hbase = (size_t)(b0 + m16) * 256 + (size_t)wv * 64 + (size_t)q * 2;

    __syncthreads();

    for (int t = 0; t < S_; ++t) {
        const unsigned long long* rg = (const unsigned long long*)
            (ring + (size_t)((t - 1) & 3) * RING_SLOT);
        unsigned long long w[16];
        if (t > 0) {
            // issue the h poll-loads EARLY; x work below hides their latency
#pragma unroll
            for (int kk = 0; kk < 8; ++kk) {
                w[2 * kk]     = __hip_atomic_load(rg + hbase + kk * 8,
                                  __ATOMIC_RELAXED, __HIP_MEMORY_SCOPE_AGENT);
                w[2 * kk + 1] = __hip_atomic_load(rg + hbase + kk * 8 + 1,
                                  __ATOMIC_RELAXED, __HIP_MEMORY_SCOPE_AGENT);
            }
        }

        // ---- x-part MFMA (K = 0..511): A-frags straight from global (cached)
        f32x4 acc0 = {0.f, 0.f, 0.f, 0.f}, acc1 = {0.f, 0.f, 0.f, 0.f};
        {
            bf16x8 ax[4];
            const unsigned short* xrow =
                xb + ((size_t)(b0 + m16) * S_ + t) * DIN + q * 8;
#pragma unroll
            for (int kk = 0; kk < 4; ++kk)
                ax[kk] = *(const bf16x8*)(xrow + (wv * 4 + kk) * 32);
#pragma unroll
            for (int kk = 0; kk < 4; ++kk) {
                int kc = wv * 4 + kk;
                bf16x8 bb0 = *(const bf16x8*)(ldsW + ((kc * 2 + 0) * 64 + lane) * 8);
                bf16x8 bb1 = *(const bf16x8*)(ldsW + ((kc * 2 + 1) * 64 + lane) * 8);
                acc0 = __builtin_amdgcn_mfma_f32_16x16x32_bf16(ax[kk], bb0, acc0, 0, 0, 0);
                acc1 = __builtin_amdgcn_mfma_f32_16x16x32_bf16(ax[kk], bb1, acc1, 0, 0, 0);
            }
        }

        // ---- h-part A-fragments: data IS the flag (sentinel poll, per wave)
        bf16x8 ah[8];
        if (t == 0) {
            const float* hrow = h0 + (size_t)(b0 + m16) * DH + q * 8;
#pragma unroll
            for (int kk = 0; kk < 8; ++kk) {
                const float* p = hrow + (wv * 8 + kk) * 32;
                float4 lo = *(const float4*)(p);
                float4 hi = *(const float4*)(p + 4);
                union { ushort8v s; bf16x8 v; } cv;
                cv.s[0] = f2bf(lo.x); cv.s[1] = f2bf(lo.y);
                cv.s[2] = f2bf(lo.z); cv.s[3] = f2bf(lo.w);
                cv.s[4] = f2bf(hi.x); cv.s[5] = f2bf(hi.y);
                cv.s[6] = f2bf(hi.z); cv.s[7] = f2bf(hi.w);
                ah[kk] = cv.v;
            }
        } else {
            for (;;) {
                int ok = 1;
#pragma unroll
                for (int j = 0; j < 16; ++j)
                    ok &= ((unsigned)(w[j] & 0xFFFFFFFFull) != SENT) &
                          ((unsigned)(w[j] >> 32) != SENT);
                if (__all(ok)) break;
                __builtin_amdgcn_s_sleep(1);
#pragma unroll
                for (int kk = 0; kk < 8; ++kk) {
                    w[2 * kk]     = __hip_atomic_load(rg + hbase + kk * 8,
                                      __ATOMIC_RELAXED, __HIP_MEMORY_SCOPE_AGENT);
                    w[2 * kk + 1] = __hip_atomic_load(rg + hbase + kk * 8 + 1,
                                      __ATOMIC_RELAXED, __HIP_MEMORY_SCOPE_AGENT);
                }
            }
#pragma unroll
            for (int kk = 0; kk < 8; ++kk) {
                union { unsigned long long u[2]; bf16x8 v; } cv;
                cv.u[0] = w[2 * kk]; cv.u[1] = w[2 * kk + 1];
                ah[kk] = cv.v;
            }
        }

        // ---- h-part MFMA (K = 512..1535): K-split over 4 waves
#pragma unroll
        for (int kk = 0; kk < 8; ++kk) {
            int kc = NKX + wv * 8 + kk;
            bf16x8 bb0 = *(const bf16x8*)(ldsW + ((kc * 2 + 0) * 64 + lane) * 8);
            bf16x8 bb1 = *(const bf16x8*)(ldsW + ((kc * 2 + 1) * 64 + lane) * 8);
            acc0 = __builtin_amdgcn_mfma_f32_16x16x32_bf16(ah[kk], bb0, acc0, 0, 0, 0);
            acc1 = __builtin_amdgcn_mfma_f32_16x16x32_bf16(ah[kk], bb1, acc1, 0, 0, 0);
        }
#pragma unroll
        for (int i = 0; i < 4; ++i) {
            ldsP[wv * (16 * SMEM_P_PITCH) + (q * 4 + i) * SMEM_P_PITCH + m16]      = acc0[i];
            ldsP[wv * (16 * SMEM_P_PITCH) + (q * 4 + i) * SMEM_P_PITCH + 16 + m16] = acc1[i];
        }
        __syncthreads();   // A: partials visible (also vmcnt-drains our reset store)

        // ---- epilogue: reduce 4 wave-partials
        float s0 = bias0, s1 = bias1;
#pragma unroll
        for (int wq = 0; wq < 4; ++wq) {
            const float2 p = *(const float2*)(ldsP + wq * (16 * SMEM_P_PITCH) +
                                              em * SMEM_P_PITCH + np);
            s0 += p.x; s1 += p.y;
        }
        __syncthreads();   // B: ldsP reads done before next iter's writes

        float v0 = fast_tanh(s0), v1 = fast_tanh(s1);

        // ring publish: the data itself is the signal
        unsigned int pk = (unsigned int)f2bf(v0) | ((unsigned int)f2bf(v1) << 16);
        const size_t widx = (size_t)(b0 + em) * (DH / 2) + (size_t)(c0 + np) / 2;
        __hip_atomic_store(ring + (size_t)(t & 3) * RING_SLOT + widx, pk,
                           __ATOMIC_RELAXED, __HIP_MEMORY_SCOPE_AGENT);

        // reset the word we wrote at t-2 back to sentinel (slot reused at t+2;
        // this store is vmcnt-drained by our next barrier A, hence visible
        // before our h_t publish that step-(t+2) producers must observe)
        if (t >= 2)
            __hip_atomic_store(ring + (size_t)((t - 2) & 3) * RING_SLOT + widx, SENT,
                               __ATOMIC_RELAXED, __HIP_MEMORY_SCOPE_AGENT);

        // HBM out-store last: off the inter-WG critical chain
        float2 ov; ov.x = v0; ov.y = v1;
        *(float2*)(out + ((size_t)(b0 + em) * S_ + t) * DH + c0 + np) = ov;
        if (t == S_ - 1)
            *(float2*)(out + (size_t)B_ * S_ * DH + (size_t)(b0 + em) * DH + c0 + np) = ov;
    }
}

extern "C" void kernel_launch(void* const* d_in, const int* in_sizes, int n_in,
                              void* d_out, int out_size, void* d_ws, size_t ws_size,
                              hipStream_t stream) {
    const float* x  = (const float*)d_in[0];   // [64][512][512]
    const float* h0 = (const float*)d_in[1];   // [64][1024]
    const float* W  = (const float*)d_in[2];   // [1536][1024]
    const float* b  = (const float*)d_in[3];   // [1024]
    float* out = (float*)d_out;

    // workspace layout
    char* ws = (char*)d_ws;
    unsigned int* ring = (unsigned int*)ws;                         // 512 KB
    unsigned short* xb = (unsigned short*)(ws + (size_t)NSLOT * RING_SLOT * 4); // 32 MB
    unsigned short* wswz = xb + (size_t)B_ * S_ * DIN;              // 3 MB

    (void)hipFuncSetAttribute((const void*)k_rnn,
                              hipFuncAttributeMaxDynamicSharedMemorySize,
                              SMEM_BYTES);

    hipMemsetAsync(ring, 0xFF, (size_t)NSLOT * RING_SLOT * 4, stream);
    k_cvt_bf16<<<(B_ * S_ * DIN / 4 + 255) / 256, 256, 0, stream>>>(x, xb, B_ * S_ * DIN / 4);
    k_swz_w<<<(NKC * 64 * 64) / 256, 256, 0, stream>>>(W, wswz);
    k_rnn<<<NBG * NCG, 256, SMEM_BYTES, stream>>>(xb, wswz, h0, b, out, ring);
}